// Round 9
// baseline (227.465 us; speedup 1.0000x reference)
//
#include <hip/hip_runtime.h>
#include <math.h>

#define NSEQ 256
#define SLEN 48
#define DIN  64
#define NCH  8
#define LOG2E 1.4426950408889634f

typedef _Float16 half8  __attribute__((ext_vector_type(8)));
typedef __fp16   fp16x2 __attribute__((ext_vector_type(2)));
typedef float    f32x4  __attribute__((ext_vector_type(4)));

union U8 { _Float16 h[8]; uint4 u; unsigned int w[4]; half8 v; };
union U2 { _Float16 h[4]; uint2 u; };
union UPK { fp16x2 f; unsigned int i; };

// ---------------- K1: mask bits + out[:,127] ----------------
__global__ __launch_bounds__(256) void mask_k(const int* __restrict__ mask,
                                              unsigned long long* __restrict__ mask64,
                                              float* __restrict__ out) {
    int wid  = (blockIdx.x * 256 + threadIdx.x) >> 6;
    int lane = threadIdx.x & 63;
    if (wid >= NSEQ) return;
    int mv = (lane < SLEN) ? mask[wid * SLEN + lane] : 0;
    unsigned long long b = __ballot(mv != 0);
    if (lane == 0) { mask64[wid] = b; out[wid * 128 + 127] = b ? 1.f : 0.f; }
}

// ---------------- K2: W -> f16 fragment layout ----------------
// perm=0 (W1, A-op of L1):  row = 32kt + 8g + e
// perm=1 (W2, B-op of L2):  row = 32kt + 16(e>>2) + 4g + (e&3)   [k-axis perm π]
__global__ __launch_bounds__(256) void wprep_k(const float* __restrict__ W,
                                               unsigned short* __restrict__ Wf,
                                               float scale, int perm) {
    __shared__ float wl[DIN * DIN];
    int d = blockIdx.x;
    const float* src = W + (size_t)d * DIN * DIN;
    for (int k = threadIdx.x; k < DIN * DIN / 4; k += 256)
        ((float4*)wl)[k] = ((const float4*)src)[k];
    __syncthreads();
    for (int rr = 0; rr < 2; ++rr) {
        int idx = threadIdx.x * 2 + rr;
        int fid = idx >> 6, l = idx & 63;
        int mt = fid >> 1, kt = fid & 1, g = l >> 4, c = l & 15;
        U8 t;
        #pragma unroll
        for (int e = 0; e < 8; ++e) {
            int row = perm ? (32 * kt + 16 * (e >> 2) + 4 * g + (e & 3))
                           : (32 * kt + 8 * g + e);
            t.h[e] = (_Float16)(wl[row * DIN + (16 * mt + c)] * scale);
        }
        *(uint4*)(Wf + ((size_t)(d * 8 + fid) * 64 + l) * 8) = t.u;
    }
}

// ---------------- K3a: embedding -> f16, row-major, chunk-swizzled ----------
__global__ __launch_bounds__(256) void embed_k(const float* __restrict__ values,
                                               const float* __restrict__ times,
                                               const float* __restrict__ omega,
                                               const float* __restrict__ alpha,
                                               unsigned short* __restrict__ zh) {
    int id = blockIdx.x * 256 + threadIdx.x;
    int ch = id & 7, ns = id >> 3;
    if (ns >= NSEQ * SLEN) return;
    int s = ns % SLEN;
    float t = times[ns];
    U8 o;
    #pragma unroll
    for (int e = 0; e < 8; ++e) {
        int i = ch * 8 + e;
        float r;
        if (i == 0)       r = omega[0] * t + alpha[0];
        else if (i == 63) r = values[ns];
        else              r = __sinf(t * omega[i] + alpha[i]);
        o.h[e] = (_Float16)r;
    }
    int csw = ch ^ (s & 7);
    *(uint4*)(zh + (size_t)ns * 64 + csw * 8) = o.u;
}

// ---------------- K3b: transposed embedding zhT[n][j][s], row stride 56 -----
__global__ __launch_bounds__(256) void embedT_k(const float* __restrict__ values,
                                                const float* __restrict__ times,
                                                const float* __restrict__ omega,
                                                const float* __restrict__ alpha,
                                                unsigned short* __restrict__ zhT) {
    int id = blockIdx.x * 256 + threadIdx.x;
    int unit = id & 511, n = id >> 9;
    int sc = unit >> 6;
    if (sc >= 6) return;
    int j = unit & 63;
    int s0 = sc * 8;
    const float* tp = times + n * SLEN + s0;
    float4 t0 = *(const float4*)tp, t1 = *(const float4*)(tp + 4);
    float tv[8] = {t0.x, t0.y, t0.z, t0.w, t1.x, t1.y, t1.z, t1.w};
    U8 o;
    if (j == 0) {
        float om = omega[0], al = alpha[0];
        #pragma unroll
        for (int e = 0; e < 8; ++e) o.h[e] = (_Float16)(om * tv[e] + al);
    } else if (j == 63) {
        const float* vp = values + n * SLEN + s0;
        float4 v0 = *(const float4*)vp, v1 = *(const float4*)(vp + 4);
        float vv[8] = {v0.x, v0.y, v0.z, v0.w, v1.x, v1.y, v1.z, v1.w};
        #pragma unroll
        for (int e = 0; e < 8; ++e) o.h[e] = (_Float16)vv[e];
    } else {
        float om = omega[j], al = alpha[j];
        #pragma unroll
        for (int e = 0; e < 8; ++e) o.h[e] = (_Float16)__sinf(tv[e] * om + al);
    }
    *(uint4*)(zhT + (size_t)n * 3584 + j * 56 + s0) = o.u;
}

// ---------------- K4: main fused kernel ----------------
// grid (32,32): bx = n-chunk (8 n's), by = d-quad. 4 waves/block.
// No hbuf: L1 D-layout feeds L2 A-fragments directly via k-axis perm π
// (baked into W2's prep). LDS 26KB -> 4 blocks/CU = 16 waves/CU.
__global__ __launch_bounds__(256, 4) void filter_k(
    const unsigned short* __restrict__ zh,
    const unsigned short* __restrict__ zhT,
    const unsigned long long* __restrict__ mask64,
    const unsigned short* __restrict__ w1f, const unsigned short* __restrict__ w2f,
    const float* __restrict__ b1, const float* __restrict__ b2,
    float* __restrict__ out)
{
    const int tid = threadIdx.x;
    const int w = tid >> 6, lane = tid & 63;
    const int g = lane >> 4, c = lane & 15;
    const int d = blockIdx.y * 4 + w;
    const bool valid = (d < 127);
    const int nb = blockIdx.x * NCH;

    __shared__ __align__(16) unsigned short zbuf[2][SLEN * DIN];  // 2 x 6KB
    __shared__ __align__(16) unsigned short ztb[2][DIN * 56];     // 2 x 7KB

    // ---- prologue: stage n0 (384 z-uint4 + 448 zT-uint4, 256 thr)
    {
        const uint4* zs = (const uint4*)(zh  + (size_t)nb * 3072);
        const uint4* ts = (const uint4*)(zhT + (size_t)nb * 3584);
        ((uint4*)zbuf[0])[tid] = zs[tid];
        if (tid < 128) ((uint4*)zbuf[0])[tid + 256] = zs[tid + 256];
        ((uint4*)ztb[0])[tid] = ts[tid];
        if (tid < 192) ((uint4*)ztb[0])[tid + 256] = ts[tid + 256];
    }

    // per-d constants
    half8 w1fr[8], w2fr[8];
    float b1v[16], b2v[4];
    if (valid) {
        #pragma unroll
        for (int f = 0; f < 8; ++f) {
            w1fr[f] = *(const half8*)(w1f + ((size_t)(d * 8 + f) * 64 + lane) * 8);
            w2fr[f] = *(const half8*)(w2f + ((size_t)(d * 8 + f) * 64 + lane) * 8);
        }
        #pragma unroll
        for (int hm = 0; hm < 4; ++hm)
            #pragma unroll
            for (int r = 0; r < 4; ++r)
                b1v[hm * 4 + r] = b1[d * DIN + 16 * hm + 4 * g + r];
        #pragma unroll
        for (int jt = 0; jt < 4; ++jt)
            b2v[jt] = b2[d * DIN + 16 * jt + c] * LOG2E;
    }

    // hoisted LDS offsets
    int zoff[2][3];   // b128 frag reads: row s=16st+c, chunk (4kt+g)^(s&7)
    #pragma unroll
    for (int kt = 0; kt < 2; ++kt)
        #pragma unroll
        for (int st = 0; st < 3; ++st) {
            int s = 16 * st + c;
            zoff[kt][st] = s * 64 + (((4 * kt + g) ^ (s & 7)) << 3);
        }
    const int ztbase = c * 56 + 4 * g;   // zT read base: row j=16jt+c, s=16st+4g

    __syncthreads();

    int cur = 0;
    for (int ni = 0; ni < NCH; ++ni) {
        const int n = nb + ni;
        // ---- issue next-n loads early (T14)
        uint4 sg0, sg1, sg2, sg3;
        if (ni + 1 < NCH) {
            const uint4* zs = (const uint4*)(zh  + (size_t)(n + 1) * 3072);
            const uint4* ts = (const uint4*)(zhT + (size_t)(n + 1) * 3584);
            sg0 = zs[tid];
            if (tid < 128) sg1 = zs[tid + 256];
            sg2 = ts[tid];
            if (tid < 192) sg3 = ts[tid + 256];
        }

        if (valid) {
            const unsigned short* zl = zbuf[cur];
            const unsigned short* zt = ztb[cur];

            // mask -> {0,1} floats per (st, r): s = 16st+4g+r
            unsigned long long mw = mask64[n];
            float mf[3][4];
            #pragma unroll
            for (int st = 0; st < 3; ++st)
                #pragma unroll
                for (int r = 0; r < 4; ++r)
                    mf[st][r] = (float)((mw >> (16 * st + 4 * g + r)) & 1ull);

            // ---- layer 1: H^T = W1^T x Z^T  (D: col=s=16st+c, row=i=16hm+4g+r)
            half8 zf[2][3];
            #pragma unroll
            for (int kt = 0; kt < 2; ++kt)
                #pragma unroll
                for (int st = 0; st < 3; ++st)
                    zf[kt][st] = *(const half8*)(zl + zoff[kt][st]);
            f32x4 aH[4][3];
            #pragma unroll
            for (int hm = 0; hm < 4; ++hm)
                #pragma unroll
                for (int st = 0; st < 3; ++st) {
                    aH[hm][st] = (f32x4){b1v[hm * 4 + 0], b1v[hm * 4 + 1],
                                         b1v[hm * 4 + 2], b1v[hm * 4 + 3]};
                    #pragma unroll
                    for (int kt = 0; kt < 2; ++kt)
                        aH[hm][st] = __builtin_amdgcn_mfma_f32_16x16x32_f16(
                            w1fr[hm * 2 + kt], zf[kt][st], aH[hm][st], 0, 0, 0);
                }
            // relu -> packed f16 pairs, all in registers:
            // pk[hm][st][p] = (H[s][16hm+4g+2p+0], H[s][16hm+4g+2p+1])
            unsigned int pk[4][3][2];
            #pragma unroll
            for (int hm = 0; hm < 4; ++hm)
                #pragma unroll
                for (int st = 0; st < 3; ++st) {
                    float r0 = fmaxf(aH[hm][st][0], 0.f), r1 = fmaxf(aH[hm][st][1], 0.f);
                    float r2 = fmaxf(aH[hm][st][2], 0.f), r3 = fmaxf(aH[hm][st][3], 0.f);
                    UPK a, b;
                    a.f = __builtin_amdgcn_cvt_pkrtz(r0, r1);
                    b.f = __builtin_amdgcn_cvt_pkrtz(r2, r3);
                    pk[hm][st][0] = a.i;
                    pk[hm][st][1] = b.i;
                }

            // ---- layer 2 (swapped, k-permuted): logits = H x W2
            // A-frag (kt,st) = {pk[2kt][st][0], pk[2kt][st][1],
            //                   pk[2kt+1][st][0], pk[2kt+1][st][1]}  (lane-local!)
            f32x4 aL[4][3];
            #pragma unroll
            for (int jt = 0; jt < 4; ++jt)
                #pragma unroll
                for (int st = 0; st < 3; ++st) {
                    aL[jt][st] = (f32x4){b2v[jt], b2v[jt], b2v[jt], b2v[jt]};
                    #pragma unroll
                    for (int kt = 0; kt < 2; ++kt) {
                        U8 hfu;
                        hfu.w[0] = pk[2 * kt + 0][st][0];
                        hfu.w[1] = pk[2 * kt + 0][st][1];
                        hfu.w[2] = pk[2 * kt + 1][st][0];
                        hfu.w[3] = pk[2 * kt + 1][st][1];
                        aL[jt][st] = __builtin_amdgcn_mfma_f32_16x16x32_f16(
                            hfu.v, w2fr[jt * 2 + kt], aL[jt][st], 0, 0, 0);
                    }
                }

            // ---- softmax over s (in-lane + 2 shfl per jt) and weighted sum
            float part = 0.f;
            #pragma unroll
            for (int jt = 0; jt < 4; ++jt) {
                float e[3][4];
                float den = 0.f;
                #pragma unroll
                for (int st = 0; st < 3; ++st)
                    #pragma unroll
                    for (int r = 0; r < 4; ++r) {
                        float v = exp2f(aL[jt][st][r]) * mf[st][r];
                        e[st][r] = v;
                        den += v;
                    }
                den += __shfl_xor(den, 16);
                den += __shfl_xor(den, 32);
                float num = 0.f;
                #pragma unroll
                for (int st = 0; st < 3; ++st) {
                    U2 zu;
                    zu.u = *(const uint2*)(zt + ztbase + jt * 896 + st * 16);
                    #pragma unroll
                    for (int r = 0; r < 4; ++r)
                        num = fmaf(e[st][r], (float)zu.h[r], num);
                }
                part = fmaf(num, __builtin_amdgcn_rcpf(den), part);
            }
            #pragma unroll
            for (int x = 1; x < 64; x <<= 1) part += __shfl_xor(part, x);
            if (lane == 0) out[n * 128 + d] = part;
        }

        // ---- commit-late into the other buffer, then barrier
        if (ni + 1 < NCH) {
            ((uint4*)zbuf[cur ^ 1])[tid] = sg0;
            if (tid < 128) ((uint4*)zbuf[cur ^ 1])[tid + 256] = sg1;
            ((uint4*)ztb[cur ^ 1])[tid] = sg2;
            if (tid < 192) ((uint4*)ztb[cur ^ 1])[tid + 256] = sg3;
            __syncthreads();
        }
        cur ^= 1;
    }
}

extern "C" void kernel_launch(void* const* d_in, const int* in_sizes, int n_in,
                              void* d_out, int out_size, void* d_ws, size_t ws_size,
                              hipStream_t stream) {
    const float* values = (const float*)d_in[0];
    const float* times  = (const float*)d_in[1];
    const int*   mask   = (const int*)d_in[2];
    const float* omega  = (const float*)d_in[3];
    const float* alpha  = (const float*)d_in[4];
    const float* W1     = (const float*)d_in[5];
    const float* b1     = (const float*)d_in[6];
    const float* W2     = (const float*)d_in[7];
    const float* b2     = (const float*)d_in[8];
    float* out = (float*)d_out;

    unsigned short* zh  = (unsigned short*)d_ws;                 // 786432 f16
    unsigned short* zhT = zh  + (size_t)786432;                  // 917504 f16
    unsigned short* w1f = zhT + (size_t)917504;                  // 520192 f16
    unsigned short* w2f = w1f + (size_t)520192;                  // 520192 f16
    unsigned long long* m64 = (unsigned long long*)(w2f + (size_t)520192);

    mask_k <<<dim3(64),  dim3(256), 0, stream>>>(mask, m64, out);
    embed_k<<<dim3(384), dim3(256), 0, stream>>>(values, times, omega, alpha, zh);
    embedT_k<<<dim3(512), dim3(256), 0, stream>>>(values, times, omega, alpha, zhT);
    wprep_k<<<dim3(127), dim3(256), 0, stream>>>(W1, w1f, 1.0f, 0);
    wprep_k<<<dim3(127), dim3(256), 0, stream>>>(W2, w2f, LOG2E, 1);
    filter_k<<<dim3(NSEQ / NCH, 32), dim3(256), 0, stream>>>(
        zh, zhT, m64, w1f, w2f, b1, b2, out);
}

// Round 10
// 79.975 us; speedup vs baseline: 2.8442x; 2.8442x over previous
//
#include <hip/hip_runtime.h>
#include <math.h>

#define NSEQ 256
#define SLEN 48
#define DIN  64
#define NCH  8
#define LOG2E 1.4426950408889634f

typedef _Float16 half8  __attribute__((ext_vector_type(8)));
typedef __fp16   fp16x2 __attribute__((ext_vector_type(2)));
typedef float    f32x4  __attribute__((ext_vector_type(4)));

union U8 { _Float16 h[8]; uint4 u; unsigned int w[4]; half8 v; };
union U2 { _Float16 h[4]; uint2 u; };
union UPK { fp16x2 f; unsigned int i; };

// ---------------- K1: mask bits + out[:,127] ----------------
__global__ __launch_bounds__(256) void mask_k(const int* __restrict__ mask,
                                              unsigned long long* __restrict__ mask64,
                                              float* __restrict__ out) {
    int wid  = (blockIdx.x * 256 + threadIdx.x) >> 6;
    int lane = threadIdx.x & 63;
    if (wid >= NSEQ) return;
    int mv = (lane < SLEN) ? mask[wid * SLEN + lane] : 0;
    unsigned long long b = __ballot(mv != 0);
    if (lane == 0) { mask64[wid] = b; out[wid * 128 + 127] = b ? 1.f : 0.f; }
}

// ---------------- K2: W -> f16 fragment layout ----------------
// perm=0 (W1, A-op of L1):  row = 32kt + 8g + e
// perm=1 (W2, B-op of L2):  row = 32kt + 16(e>>2) + 4g + (e&3)   [k-axis perm π]
__global__ __launch_bounds__(256) void wprep_k(const float* __restrict__ W,
                                               unsigned short* __restrict__ Wf,
                                               float scale, int perm) {
    __shared__ float wl[DIN * DIN];
    int d = blockIdx.x;
    const float* src = W + (size_t)d * DIN * DIN;
    for (int k = threadIdx.x; k < DIN * DIN / 4; k += 256)
        ((float4*)wl)[k] = ((const float4*)src)[k];
    __syncthreads();
    for (int rr = 0; rr < 2; ++rr) {
        int idx = threadIdx.x * 2 + rr;
        int fid = idx >> 6, l = idx & 63;
        int mt = fid >> 1, kt = fid & 1, g = l >> 4, c = l & 15;
        U8 t;
        #pragma unroll
        for (int e = 0; e < 8; ++e) {
            int row = perm ? (32 * kt + 16 * (e >> 2) + 4 * g + (e & 3))
                           : (32 * kt + 8 * g + e);
            t.h[e] = (_Float16)(wl[row * DIN + (16 * mt + c)] * scale);
        }
        *(uint4*)(Wf + ((size_t)(d * 8 + fid) * 64 + l) * 8) = t.u;
    }
}

// ---------------- K3a: embedding -> f16, row-major, chunk-swizzled ----------
__global__ __launch_bounds__(256) void embed_k(const float* __restrict__ values,
                                               const float* __restrict__ times,
                                               const float* __restrict__ omega,
                                               const float* __restrict__ alpha,
                                               unsigned short* __restrict__ zh) {
    int id = blockIdx.x * 256 + threadIdx.x;
    int ch = id & 7, ns = id >> 3;
    if (ns >= NSEQ * SLEN) return;
    int s = ns % SLEN;
    float t = times[ns];
    U8 o;
    #pragma unroll
    for (int e = 0; e < 8; ++e) {
        int i = ch * 8 + e;
        float r;
        if (i == 0)       r = omega[0] * t + alpha[0];
        else if (i == 63) r = values[ns];
        else              r = __sinf(t * omega[i] + alpha[i]);
        o.h[e] = (_Float16)r;
    }
    int csw = ch ^ (s & 7);
    *(uint4*)(zh + (size_t)ns * 64 + csw * 8) = o.u;
}

// ---------------- K3b: transposed embedding zhT[n][j][s], row stride 56 -----
__global__ __launch_bounds__(256) void embedT_k(const float* __restrict__ values,
                                                const float* __restrict__ times,
                                                const float* __restrict__ omega,
                                                const float* __restrict__ alpha,
                                                unsigned short* __restrict__ zhT) {
    int id = blockIdx.x * 256 + threadIdx.x;
    int unit = id & 511, n = id >> 9;
    int sc = unit >> 6;
    if (sc >= 6) return;
    int j = unit & 63;
    int s0 = sc * 8;
    const float* tp = times + n * SLEN + s0;
    float4 t0 = *(const float4*)tp, t1 = *(const float4*)(tp + 4);
    float tv[8] = {t0.x, t0.y, t0.z, t0.w, t1.x, t1.y, t1.z, t1.w};
    U8 o;
    if (j == 0) {
        float om = omega[0], al = alpha[0];
        #pragma unroll
        for (int e = 0; e < 8; ++e) o.h[e] = (_Float16)(om * tv[e] + al);
    } else if (j == 63) {
        const float* vp = values + n * SLEN + s0;
        float4 v0 = *(const float4*)vp, v1 = *(const float4*)(vp + 4);
        float vv[8] = {v0.x, v0.y, v0.z, v0.w, v1.x, v1.y, v1.z, v1.w};
        #pragma unroll
        for (int e = 0; e < 8; ++e) o.h[e] = (_Float16)vv[e];
    } else {
        float om = omega[j], al = alpha[j];
        #pragma unroll
        for (int e = 0; e < 8; ++e) o.h[e] = (_Float16)__sinf(tv[e] * om + al);
    }
    *(uint4*)(zhT + (size_t)n * 3584 + j * 56 + s0) = o.u;
}

// ---------------- K4: main fused kernel ----------------
// grid (32,32): bx = n-chunk (8 n's), by = d-quad. 4 waves/block.
// No hbuf: L1 D-layout feeds L2 A-fragments directly via k-axis perm π
// (baked into W2's prep). LDS 26KB.
// launch_bounds(256,2): VGPR cap 128 (kernel ~112, no spill — w>=3 caps at
// 256/w and forces spills, measured rounds 4/5/7/9). HW gives 4 waves/SIMD
// at <=128 VGPRs; 4 blocks/CU from LDS -> 16 waves/CU.
__global__ __launch_bounds__(256, 2) void filter_k(
    const unsigned short* __restrict__ zh,
    const unsigned short* __restrict__ zhT,
    const unsigned long long* __restrict__ mask64,
    const unsigned short* __restrict__ w1f, const unsigned short* __restrict__ w2f,
    const float* __restrict__ b1, const float* __restrict__ b2,
    float* __restrict__ out)
{
    const int tid = threadIdx.x;
    const int w = tid >> 6, lane = tid & 63;
    const int g = lane >> 4, c = lane & 15;
    const int d = blockIdx.y * 4 + w;
    const bool valid = (d < 127);
    const int nb = blockIdx.x * NCH;

    __shared__ __align__(16) unsigned short zbuf[2][SLEN * DIN];  // 2 x 6KB
    __shared__ __align__(16) unsigned short ztb[2][DIN * 56];     // 2 x 7KB

    // ---- prologue: stage n0 (384 z-uint4 + 448 zT-uint4, 256 thr)
    {
        const uint4* zs = (const uint4*)(zh  + (size_t)nb * 3072);
        const uint4* ts = (const uint4*)(zhT + (size_t)nb * 3584);
        ((uint4*)zbuf[0])[tid] = zs[tid];
        if (tid < 128) ((uint4*)zbuf[0])[tid + 256] = zs[tid + 256];
        ((uint4*)ztb[0])[tid] = ts[tid];
        if (tid < 192) ((uint4*)ztb[0])[tid + 256] = ts[tid + 256];
    }

    // per-d constants
    half8 w1fr[8], w2fr[8];
    float b1v[16], b2v[4];
    if (valid) {
        #pragma unroll
        for (int f = 0; f < 8; ++f) {
            w1fr[f] = *(const half8*)(w1f + ((size_t)(d * 8 + f) * 64 + lane) * 8);
            w2fr[f] = *(const half8*)(w2f + ((size_t)(d * 8 + f) * 64 + lane) * 8);
        }
        #pragma unroll
        for (int hm = 0; hm < 4; ++hm)
            #pragma unroll
            for (int r = 0; r < 4; ++r)
                b1v[hm * 4 + r] = b1[d * DIN + 16 * hm + 4 * g + r];
        #pragma unroll
        for (int jt = 0; jt < 4; ++jt)
            b2v[jt] = b2[d * DIN + 16 * jt + c] * LOG2E;
    }

    // hoisted LDS offsets
    int zoff[2][3];   // b128 frag reads: row s=16st+c, chunk (4kt+g)^(s&7)
    #pragma unroll
    for (int kt = 0; kt < 2; ++kt)
        #pragma unroll
        for (int st = 0; st < 3; ++st) {
            int s = 16 * st + c;
            zoff[kt][st] = s * 64 + (((4 * kt + g) ^ (s & 7)) << 3);
        }
    const int ztbase = c * 56 + 4 * g;   // zT read base: row j=16jt+c, s=16st+4g

    __syncthreads();

    int cur = 0;
    for (int ni = 0; ni < NCH; ++ni) {
        const int n = nb + ni;
        // ---- issue next-n loads early (T14)
        uint4 sg0, sg1, sg2, sg3;
        if (ni + 1 < NCH) {
            const uint4* zs = (const uint4*)(zh  + (size_t)(n + 1) * 3072);
            const uint4* ts = (const uint4*)(zhT + (size_t)(n + 1) * 3584);
            sg0 = zs[tid];
            if (tid < 128) sg1 = zs[tid + 256];
            sg2 = ts[tid];
            if (tid < 192) sg3 = ts[tid + 256];
        }

        if (valid) {
            const unsigned short* zl = zbuf[cur];
            const unsigned short* zt = ztb[cur];

            // mask -> {0,1} floats per (st, r): s = 16st+4g+r
            unsigned long long mw = mask64[n];
            float mf[3][4];
            #pragma unroll
            for (int st = 0; st < 3; ++st)
                #pragma unroll
                for (int r = 0; r < 4; ++r)
                    mf[st][r] = (float)((mw >> (16 * st + 4 * g + r)) & 1ull);

            // ---- layer 1: H^T = W1^T x Z^T  (D: col=s=16st+c, row=i=16hm+4g+r)
            half8 zf[2][3];
            #pragma unroll
            for (int kt = 0; kt < 2; ++kt)
                #pragma unroll
                for (int st = 0; st < 3; ++st)
                    zf[kt][st] = *(const half8*)(zl + zoff[kt][st]);
            f32x4 aH[4][3];
            #pragma unroll
            for (int hm = 0; hm < 4; ++hm)
                #pragma unroll
                for (int st = 0; st < 3; ++st) {
                    aH[hm][st] = (f32x4){b1v[hm * 4 + 0], b1v[hm * 4 + 1],
                                         b1v[hm * 4 + 2], b1v[hm * 4 + 3]};
                    #pragma unroll
                    for (int kt = 0; kt < 2; ++kt)
                        aH[hm][st] = __builtin_amdgcn_mfma_f32_16x16x32_f16(
                            w1fr[hm * 2 + kt], zf[kt][st], aH[hm][st], 0, 0, 0);
                }
            // relu -> packed f16 pairs, all in registers:
            // pk[hm][st][p] = (H[s][16hm+4g+2p+0], H[s][16hm+4g+2p+1])
            unsigned int pk[4][3][2];
            #pragma unroll
            for (int hm = 0; hm < 4; ++hm)
                #pragma unroll
                for (int st = 0; st < 3; ++st) {
                    float r0 = fmaxf(aH[hm][st][0], 0.f), r1 = fmaxf(aH[hm][st][1], 0.f);
                    float r2 = fmaxf(aH[hm][st][2], 0.f), r3 = fmaxf(aH[hm][st][3], 0.f);
                    UPK a, b;
                    a.f = __builtin_amdgcn_cvt_pkrtz(r0, r1);
                    b.f = __builtin_amdgcn_cvt_pkrtz(r2, r3);
                    pk[hm][st][0] = a.i;
                    pk[hm][st][1] = b.i;
                }

            // ---- layer 2 (swapped, k-permuted): logits = H x W2
            // A-frag (kt,st) = {pk[2kt][st][0], pk[2kt][st][1],
            //                   pk[2kt+1][st][0], pk[2kt+1][st][1]}  (lane-local!)
            f32x4 aL[4][3];
            #pragma unroll
            for (int jt = 0; jt < 4; ++jt)
                #pragma unroll
                for (int st = 0; st < 3; ++st) {
                    aL[jt][st] = (f32x4){b2v[jt], b2v[jt], b2v[jt], b2v[jt]};
                    #pragma unroll
                    for (int kt = 0; kt < 2; ++kt) {
                        U8 hfu;
                        hfu.w[0] = pk[2 * kt + 0][st][0];
                        hfu.w[1] = pk[2 * kt + 0][st][1];
                        hfu.w[2] = pk[2 * kt + 1][st][0];
                        hfu.w[3] = pk[2 * kt + 1][st][1];
                        aL[jt][st] = __builtin_amdgcn_mfma_f32_16x16x32_f16(
                            hfu.v, w2fr[jt * 2 + kt], aL[jt][st], 0, 0, 0);
                    }
                }

            // ---- softmax over s (in-lane + 2 shfl per jt) and weighted sum
            float part = 0.f;
            #pragma unroll
            for (int jt = 0; jt < 4; ++jt) {
                float e[3][4];
                float den = 0.f;
                #pragma unroll
                for (int st = 0; st < 3; ++st)
                    #pragma unroll
                    for (int r = 0; r < 4; ++r) {
                        float v = exp2f(aL[jt][st][r]) * mf[st][r];
                        e[st][r] = v;
                        den += v;
                    }
                den += __shfl_xor(den, 16);
                den += __shfl_xor(den, 32);
                float num = 0.f;
                #pragma unroll
                for (int st = 0; st < 3; ++st) {
                    U2 zu;
                    zu.u = *(const uint2*)(zt + ztbase + jt * 896 + st * 16);
                    #pragma unroll
                    for (int r = 0; r < 4; ++r)
                        num = fmaf(e[st][r], (float)zu.h[r], num);
                }
                part = fmaf(num, __builtin_amdgcn_rcpf(den), part);
            }
            #pragma unroll
            for (int x = 1; x < 64; x <<= 1) part += __shfl_xor(part, x);
            if (lane == 0) out[n * 128 + d] = part;
        }

        // ---- commit-late into the other buffer, then barrier
        if (ni + 1 < NCH) {
            ((uint4*)zbuf[cur ^ 1])[tid] = sg0;
            if (tid < 128) ((uint4*)zbuf[cur ^ 1])[tid + 256] = sg1;
            ((uint4*)ztb[cur ^ 1])[tid] = sg2;
            if (tid < 192) ((uint4*)ztb[cur ^ 1])[tid + 256] = sg3;
            __syncthreads();
        }
        cur ^= 1;
    }
}

extern "C" void kernel_launch(void* const* d_in, const int* in_sizes, int n_in,
                              void* d_out, int out_size, void* d_ws, size_t ws_size,
                              hipStream_t stream) {
    const float* values = (const float*)d_in[0];
    const float* times  = (const float*)d_in[1];
    const int*   mask   = (const int*)d_in[2];
    const float* omega  = (const float*)d_in[3];
    const float* alpha  = (const float*)d_in[4];
    const float* W1     = (const float*)d_in[5];
    const float* b1     = (const float*)d_in[6];
    const float* W2     = (const float*)d_in[7];
    const float* b2     = (const float*)d_in[8];
    float* out = (float*)d_out;

    unsigned short* zh  = (unsigned short*)d_ws;                 // 786432 f16
    unsigned short* zhT = zh  + (size_t)786432;                  // 917504 f16
    unsigned short* w1f = zhT + (size_t)917504;                  // 520192 f16
    unsigned short* w2f = w1f + (size_t)520192;                  // 520192 f16
    unsigned long long* m64 = (unsigned long long*)(w2f + (size_t)520192);

    mask_k <<<dim3(64),  dim3(256), 0, stream>>>(mask, m64, out);
    embed_k<<<dim3(384), dim3(256), 0, stream>>>(values, times, omega, alpha, zh);
    embedT_k<<<dim3(512), dim3(256), 0, stream>>>(values, times, omega, alpha, zhT);
    wprep_k<<<dim3(127), dim3(256), 0, stream>>>(W1, w1f, 1.0f, 0);
    wprep_k<<<dim3(127), dim3(256), 0, stream>>>(W2, w2f, LOG2E, 1);
    filter_k<<<dim3(NSEQ / NCH, 32), dim3(256), 0, stream>>>(
        zh, zhT, m64, w1f, w2f, b1, b2, out);
}

// Round 11
// 75.753 us; speedup vs baseline: 3.0027x; 1.0557x over previous
//
#include <hip/hip_runtime.h>
#include <math.h>

#define NSEQ 256
#define SLEN 48
#define DIN  64
#define NCH  8
#define LOG2E 1.4426950408889634f

typedef _Float16 half8  __attribute__((ext_vector_type(8)));
typedef __fp16   fp16x2 __attribute__((ext_vector_type(2)));
typedef float    f32x4  __attribute__((ext_vector_type(4)));

union U8 { _Float16 h[8]; uint4 u; unsigned int w[4]; half8 v; };
union U2 { _Float16 h[4]; uint2 u; };
union UPK { fp16x2 f; unsigned int i; };

// ---------------- K1: mask bits + out[:,127] ----------------
__global__ __launch_bounds__(256) void mask_k(const int* __restrict__ mask,
                                              unsigned long long* __restrict__ mask64,
                                              float* __restrict__ out) {
    int wid  = (blockIdx.x * 256 + threadIdx.x) >> 6;
    int lane = threadIdx.x & 63;
    if (wid >= NSEQ) return;
    int mv = (lane < SLEN) ? mask[wid * SLEN + lane] : 0;
    unsigned long long b = __ballot(mv != 0);
    if (lane == 0) { mask64[wid] = b; out[wid * 128 + 127] = b ? 1.f : 0.f; }
}

// ---------------- K2: W -> f16 fragment layout ----------------
// perm=0 (W1, A-op of L1):  row = 32kt + 8g + e
// perm=1 (W2, B-op of L2):  row = 32kt + 16(e>>2) + 4g + (e&3)   [k-axis perm π]
__global__ __launch_bounds__(256) void wprep_k(const float* __restrict__ W,
                                               unsigned short* __restrict__ Wf,
                                               float scale, int perm) {
    __shared__ float wl[DIN * DIN];
    int d = blockIdx.x;
    const float* src = W + (size_t)d * DIN * DIN;
    for (int k = threadIdx.x; k < DIN * DIN / 4; k += 256)
        ((float4*)wl)[k] = ((const float4*)src)[k];
    __syncthreads();
    for (int rr = 0; rr < 2; ++rr) {
        int idx = threadIdx.x * 2 + rr;
        int fid = idx >> 6, l = idx & 63;
        int mt = fid >> 1, kt = fid & 1, g = l >> 4, c = l & 15;
        U8 t;
        #pragma unroll
        for (int e = 0; e < 8; ++e) {
            int row = perm ? (32 * kt + 16 * (e >> 2) + 4 * g + (e & 3))
                           : (32 * kt + 8 * g + e);
            t.h[e] = (_Float16)(wl[row * DIN + (16 * mt + c)] * scale);
        }
        *(uint4*)(Wf + ((size_t)(d * 8 + fid) * 64 + l) * 8) = t.u;
    }
}

// ---------------- K3a: embedding -> f16, row-major, chunk-swizzled ----------
__global__ __launch_bounds__(256) void embed_k(const float* __restrict__ values,
                                               const float* __restrict__ times,
                                               const float* __restrict__ omega,
                                               const float* __restrict__ alpha,
                                               unsigned short* __restrict__ zh) {
    int id = blockIdx.x * 256 + threadIdx.x;
    int ch = id & 7, ns = id >> 3;
    if (ns >= NSEQ * SLEN) return;
    int s = ns % SLEN;
    float t = times[ns];
    U8 o;
    #pragma unroll
    for (int e = 0; e < 8; ++e) {
        int i = ch * 8 + e;
        float r;
        if (i == 0)       r = omega[0] * t + alpha[0];
        else if (i == 63) r = values[ns];
        else              r = __sinf(t * omega[i] + alpha[i]);
        o.h[e] = (_Float16)r;
    }
    int csw = ch ^ (s & 7);
    *(uint4*)(zh + (size_t)ns * 64 + csw * 8) = o.u;
}

// ---------------- K3b: transposed embedding zhT[n][j][s], row stride 56 -----
__global__ __launch_bounds__(256) void embedT_k(const float* __restrict__ values,
                                                const float* __restrict__ times,
                                                const float* __restrict__ omega,
                                                const float* __restrict__ alpha,
                                                unsigned short* __restrict__ zhT) {
    int id = blockIdx.x * 256 + threadIdx.x;
    int unit = id & 511, n = id >> 9;
    int sc = unit >> 6;
    if (sc >= 6) return;
    int j = unit & 63;
    int s0 = sc * 8;
    const float* tp = times + n * SLEN + s0;
    float4 t0 = *(const float4*)tp, t1 = *(const float4*)(tp + 4);
    float tv[8] = {t0.x, t0.y, t0.z, t0.w, t1.x, t1.y, t1.z, t1.w};
    U8 o;
    if (j == 0) {
        float om = omega[0], al = alpha[0];
        #pragma unroll
        for (int e = 0; e < 8; ++e) o.h[e] = (_Float16)(om * tv[e] + al);
    } else if (j == 63) {
        const float* vp = values + n * SLEN + s0;
        float4 v0 = *(const float4*)vp, v1 = *(const float4*)(vp + 4);
        float vv[8] = {v0.x, v0.y, v0.z, v0.w, v1.x, v1.y, v1.z, v1.w};
        #pragma unroll
        for (int e = 0; e < 8; ++e) o.h[e] = (_Float16)vv[e];
    } else {
        float om = omega[j], al = alpha[j];
        #pragma unroll
        for (int e = 0; e < 8; ++e) o.h[e] = (_Float16)__sinf(tv[e] * om + al);
    }
    *(uint4*)(zhT + (size_t)n * 3584 + j * 56 + s0) = o.u;
}

// ---------------- K4: main fused kernel — NO LDS, NO BARRIERS ----------------
// grid (32,32): bx = n-chunk (8 n's), by = d-quad; 4 waves/block, each wave an
// independent (d, n-stream) worker. z/zT (3.3MB) + weights (4.2MB) are
// L2/L3-resident (FETCH=10MB at r10) -> read fragments directly from cache.
// 4064 waves = 15.9/CU = the 4-waves/SIMD VGPR cap; all resident, no convoys.
__global__ __launch_bounds__(256, 2) void filter_k(
    const unsigned short* __restrict__ zh,
    const unsigned short* __restrict__ zhT,
    const unsigned long long* __restrict__ mask64,
    const unsigned short* __restrict__ w1f, const unsigned short* __restrict__ w2f,
    const float* __restrict__ b1, const float* __restrict__ b2,
    float* __restrict__ out)
{
    const int tid = threadIdx.x;
    const int w = tid >> 6, lane = tid & 63;
    const int g = lane >> 4, c = lane & 15;
    const int d = blockIdx.y * 4 + w;
    if (d >= 127) return;                       // whole-wave exit; no barriers exist
    const int nb = blockIdx.x * NCH;

    // per-d constants (L2-resident, reused across 8 n's)
    half8 w1fr[8], w2fr[8];
    #pragma unroll
    for (int f = 0; f < 8; ++f) {
        w1fr[f] = *(const half8*)(w1f + ((size_t)(d * 8 + f) * 64 + lane) * 8);
        w2fr[f] = *(const half8*)(w2f + ((size_t)(d * 8 + f) * 64 + lane) * 8);
    }
    float4 b1q[4];
    #pragma unroll
    for (int hm = 0; hm < 4; ++hm)
        b1q[hm] = *(const float4*)(b1 + d * DIN + 16 * hm + 4 * g);
    float b2v[4];
    #pragma unroll
    for (int jt = 0; jt < 4; ++jt)
        b2v[jt] = b2[d * DIN + 16 * jt + c] * LOG2E;

    // hoisted global-address offsets (element units)
    int zoff[2][3];   // b128 frag reads: row s=16st+c, chunk (4kt+g)^(s&7)
    #pragma unroll
    for (int kt = 0; kt < 2; ++kt)
        #pragma unroll
        for (int st = 0; st < 3; ++st) {
            int s = 16 * st + c;
            zoff[kt][st] = s * 64 + (((4 * kt + g) ^ (s & 7)) << 3);
        }
    const int ztbase = c * 56 + 4 * g;   // zT: row j=16jt+c, s=16st+4g

    #pragma unroll 1
    for (int ni = 0; ni < NCH; ++ni) {
        const int n = nb + ni;
        const unsigned short* zl = zh  + (size_t)n * 3072;
        const unsigned short* zt = zhT + (size_t)n * 3584;

        // mask -> {0,1} floats per (st, r): s = 16st+4g+r  (mask64[n] uniform -> SMEM)
        unsigned long long mw = mask64[n];
        float mf[3][4];
        #pragma unroll
        for (int st = 0; st < 3; ++st)
            #pragma unroll
            for (int r = 0; r < 4; ++r)
                mf[st][r] = (float)((mw >> (16 * st + 4 * g + r)) & 1ull);

        // ---- layer 1: H^T = W1^T x Z^T (zf direct from L2)
        half8 zf[2][3];
        #pragma unroll
        for (int kt = 0; kt < 2; ++kt)
            #pragma unroll
            for (int st = 0; st < 3; ++st)
                zf[kt][st] = *(const half8*)(zl + zoff[kt][st]);
        f32x4 aH[4][3];
        #pragma unroll
        for (int hm = 0; hm < 4; ++hm)
            #pragma unroll
            for (int st = 0; st < 3; ++st) {
                aH[hm][st] = (f32x4){b1q[hm].x, b1q[hm].y, b1q[hm].z, b1q[hm].w};
                #pragma unroll
                for (int kt = 0; kt < 2; ++kt)
                    aH[hm][st] = __builtin_amdgcn_mfma_f32_16x16x32_f16(
                        w1fr[hm * 2 + kt], zf[kt][st], aH[hm][st], 0, 0, 0);
            }
        // relu -> packed f16 pairs, in registers
        unsigned int pk[4][3][2];
        #pragma unroll
        for (int hm = 0; hm < 4; ++hm)
            #pragma unroll
            for (int st = 0; st < 3; ++st) {
                float r0 = fmaxf(aH[hm][st][0], 0.f), r1 = fmaxf(aH[hm][st][1], 0.f);
                float r2 = fmaxf(aH[hm][st][2], 0.f), r3 = fmaxf(aH[hm][st][3], 0.f);
                UPK a, b;
                a.f = __builtin_amdgcn_cvt_pkrtz(r0, r1);
                b.f = __builtin_amdgcn_cvt_pkrtz(r2, r3);
                pk[hm][st][0] = a.i;
                pk[hm][st][1] = b.i;
            }

        // ---- layer 2 (swapped, k-permuted): logits = H x W2 (A lane-local)
        f32x4 aL[4][3];
        #pragma unroll
        for (int jt = 0; jt < 4; ++jt)
            #pragma unroll
            for (int st = 0; st < 3; ++st) {
                aL[jt][st] = (f32x4){b2v[jt], b2v[jt], b2v[jt], b2v[jt]};
                #pragma unroll
                for (int kt = 0; kt < 2; ++kt) {
                    U8 hfu;
                    hfu.w[0] = pk[2 * kt + 0][st][0];
                    hfu.w[1] = pk[2 * kt + 0][st][1];
                    hfu.w[2] = pk[2 * kt + 1][st][0];
                    hfu.w[3] = pk[2 * kt + 1][st][1];
                    aL[jt][st] = __builtin_amdgcn_mfma_f32_16x16x32_f16(
                        hfu.v, w2fr[jt * 2 + kt], aL[jt][st], 0, 0, 0);
                }
            }

        // ---- softmax over s + weighted sum; zT reads pipelined 1 jt ahead
        U2 zuc[3], zun[3];
        #pragma unroll
        for (int st = 0; st < 3; ++st)
            zuc[st].u = *(const uint2*)(zt + ztbase + 0 * 896 + st * 16);
        float part = 0.f;
        #pragma unroll
        for (int jt = 0; jt < 4; ++jt) {
            if (jt < 3) {
                #pragma unroll
                for (int st = 0; st < 3; ++st)
                    zun[st].u = *(const uint2*)(zt + ztbase + (jt + 1) * 896 + st * 16);
            }
            float e[3][4];
            float den = 0.f;
            #pragma unroll
            for (int st = 0; st < 3; ++st)
                #pragma unroll
                for (int r = 0; r < 4; ++r) {
                    float v = exp2f(aL[jt][st][r]) * mf[st][r];
                    e[st][r] = v;
                    den += v;
                }
            den += __shfl_xor(den, 16);
            den += __shfl_xor(den, 32);
            float num = 0.f;
            #pragma unroll
            for (int st = 0; st < 3; ++st)
                #pragma unroll
                for (int r = 0; r < 4; ++r)
                    num = fmaf(e[st][r], (float)zuc[st].h[r], num);
            part = fmaf(num, __builtin_amdgcn_rcpf(den), part);
            if (jt < 3) {
                #pragma unroll
                for (int st = 0; st < 3; ++st) zuc[st] = zun[st];
            }
        }
        #pragma unroll
        for (int x = 1; x < 64; x <<= 1) part += __shfl_xor(part, x);
        if (lane == 0) out[n * 128 + d] = part;
    }
}

extern "C" void kernel_launch(void* const* d_in, const int* in_sizes, int n_in,
                              void* d_out, int out_size, void* d_ws, size_t ws_size,
                              hipStream_t stream) {
    const float* values = (const float*)d_in[0];
    const float* times  = (const float*)d_in[1];
    const int*   mask   = (const int*)d_in[2];
    const float* omega  = (const float*)d_in[3];
    const float* alpha  = (const float*)d_in[4];
    const float* W1     = (const float*)d_in[5];
    const float* b1     = (const float*)d_in[6];
    const float* W2     = (const float*)d_in[7];
    const float* b2     = (const float*)d_in[8];
    float* out = (float*)d_out;

    unsigned short* zh  = (unsigned short*)d_ws;                 // 786432 f16
    unsigned short* zhT = zh  + (size_t)786432;                  // 917504 f16
    unsigned short* w1f = zhT + (size_t)917504;                  // 520192 f16
    unsigned short* w2f = w1f + (size_t)520192;                  // 520192 f16
    unsigned long long* m64 = (unsigned long long*)(w2f + (size_t)520192);

    mask_k <<<dim3(64),  dim3(256), 0, stream>>>(mask, m64, out);
    embed_k<<<dim3(384), dim3(256), 0, stream>>>(values, times, omega, alpha, zh);
    embedT_k<<<dim3(512), dim3(256), 0, stream>>>(values, times, omega, alpha, zhT);
    wprep_k<<<dim3(127), dim3(256), 0, stream>>>(W1, w1f, 1.0f, 0);
    wprep_k<<<dim3(127), dim3(256), 0, stream>>>(W2, w2f, LOG2E, 1);
    filter_k<<<dim3(NSEQ / NCH, 32), dim3(256), 0, stream>>>(
        zh, zhT, m64, w1f, w2f, b1, b2, out);
}